// Round 17
// baseline (377.586 us; speedup 1.0000x reference)
//
#include <hip/hip_runtime.h>
#include <hip/hip_bf16.h>

#define NE 4
#define HD 768
#define F2 384
#define F1 192
#define NT 131072

typedef __attribute__((ext_vector_type(8))) short bf16x8;
typedef __attribute__((ext_vector_type(4))) float f32x4;
typedef __attribute__((ext_vector_type(4))) unsigned int u32x4;

// ws layout (bytes)
#define WS_CNT_OFF 256
#define WS_BUCKET_OFF (256 + 8192)
#define WS_B1_OFF  (WS_BUCKET_OFF + NE*NT*4)      // b1s: 4*3*24*8192 = 2,359,296
#define WS_DN_OFF  (WS_B1_OFF + 2359296)          // dns: 4*6*6*8192 = 1,179,648
#define WS_ACT_OFF (WS_DN_OFF + 1179648)          // act: NT*192*2 = 50.3 MB (compact, sorted order)
// image format (8KB = 512 x 16B units): unit L: colp=L>>3 (64 col-pairs), slot=L&7,
//   v=slot^(colp&7), localcol=colp*2+(v>>2) in [0,128), k-octet=v&3

__device__ __forceinline__ unsigned short f2bf(float x) {
    unsigned int u = __float_as_uint(x);
    return (unsigned short)((u + 0x7fffu + ((u >> 16) & 1u)) >> 16);
}
__device__ __forceinline__ unsigned int pk2(float a, float b) {
    unsigned int ua = __float_as_uint(a), ub = __float_as_uint(b);
    unsigned int lo = (ua + 0x7fffu + ((ua >> 16) & 1u)) >> 16;
    unsigned int hi = (ub + 0x7fffu + ((ub >> 16) & 1u)) & 0xffff0000u;
    return lo | hi;
}
#define GLLD(srcp, dstp) \
    __builtin_amdgcn_global_load_lds((const __attribute__((address_space(1))) void*)(srcp), \
        (__attribute__((address_space(3))) void*)(dstp), 16, 0, 0)

// ---- counting-sort routing (bucket[e] sorted by token id) + expert offsets ----
__global__ void route1_kernel(const int* __restrict__ ids, int* __restrict__ cnt) {
    __shared__ int lc[NE];
    int tid = threadIdx.x;
    if (tid < NE) lc[tid] = 0;
    __syncthreads();
    int e = ids[blockIdx.x * 256 + tid];
    atomicAdd(&lc[e], 1);
    __syncthreads();
    if (tid < NE) cnt[tid * 512 + blockIdx.x] = lc[tid];
}

__global__ void route2_kernel(int* __restrict__ cnt, int* __restrict__ counts) {
    __shared__ int s[512];
    int tid = threadIdx.x;
    for (int e = 0; e < NE; ++e) {
        int orig = cnt[e * 512 + tid];
        s[tid] = orig; __syncthreads();
        #pragma unroll
        for (int off = 1; off < 512; off <<= 1) {
            int v = (tid >= off) ? s[tid - off] : 0; __syncthreads();
            s[tid] += v; __syncthreads();
        }
        cnt[e * 512 + tid] = s[tid] - orig;
        if (tid == 511) counts[e] = s[511];
        __syncthreads();
    }
    if (tid == 0) {   // eoff at counts[8..11]
        int a = 0;
        for (int e = 0; e < NE; ++e) { counts[8 + e] = a; a += counts[e]; }
    }
}

__global__ void route3_kernel(const int* __restrict__ ids, const int* __restrict__ cnt,
                              int* __restrict__ bucket) {
    __shared__ int lc[NE];
    int tid = threadIdx.x;
    if (tid < NE) lc[tid] = 0;
    __syncthreads();
    int t = blockIdx.x * 256 + tid;
    int e = ids[t];
    int r = atomicAdd(&lc[e], 1);
    bucket[e * NT + cnt[e * 512 + blockIdx.x] + r] = t;
}

// ---- B1 images: [e][nb3][ks24] 8KB; col c<64 -> gate f=nb*64+c, else up f=nb*64+c-64 ----
__global__ void b1s_kernel(const float* __restrict__ gu, unsigned short* __restrict__ b1s) {
    int idx = blockIdx.x * 256 + threadIdx.x;      // 4*3*24*512 = 147456
    int L = idx & 511; int r = idx >> 9;
    int ks = r % 24; r /= 24;
    int nb = r % 3; int e = r / 3;
    int colp = L >> 3, slot = L & 7;
    int v = slot ^ (colp & 7);
    int c = colp * 2 + (v >> 2);
    int k = ks * 32 + (v & 3) * 8;
    int gc = (c < 64) ? (nb * 64 + c) : (192 + nb * 64 + (c - 64));
    const float* src = gu + ((size_t)(e * HD + k)) * F2 + gc;
    unsigned short o[8];
    #pragma unroll
    for (int j = 0; j < 8; ++j) o[j] = f2bf(src[(size_t)j * F2]);
    *(bf16x8*)(b1s + (size_t)idx * 8) = *(const bf16x8*)o;
}

// ---- B2 images: [e][nb6][ks6] 8KB; col c -> h=nb*128+c, k=f=ks*32+(v&3)*8 ----
__global__ void dns_kernel(const float* __restrict__ dn, unsigned short* __restrict__ dns) {
    int idx = blockIdx.x * 256 + threadIdx.x;      // 4*6*6*512 = 73728
    int L = idx & 511; int r = idx >> 9;
    int ks = r % 6; r /= 6;
    int nb = r % 6; int e = r / 6;
    int colp = L >> 3, slot = L & 7;
    int v = slot ^ (colp & 7);
    int h = nb * 128 + colp * 2 + (v >> 2);
    int f = ks * 32 + (v & 3) * 8;
    const float* src = dn + ((size_t)(e * F1 + f)) * HD + h;
    unsigned short o[8];
    #pragma unroll
    for (int j = 0; j < 8; ++j) o[j] = f2bf(src[(size_t)j * HD]);
    *(bf16x8*)(dns + (size_t)idx * 8) = *(const bf16x8*)o;
}

// ======= GEMM1: 256 thr, 3 blocks/CU; block = 128 tok x 128 vcols(64 gate|64 up) =======
__global__ __launch_bounds__(256, 3)
void gemm1_kernel(const float* __restrict__ hidden, const int* __restrict__ counts,
                  const int* __restrict__ bucket, const unsigned short* __restrict__ b1s,
                  unsigned short* __restrict__ act)
{
    __shared__ __align__(16) unsigned char smem[37376];
    const unsigned LA[2] = {0u, 10240u};           // A: [128][80B] bf16-swz
    const unsigned LB[2] = {20480u, 28672u};       // B: 8KB images
    const unsigned LT = 36864u;

    int bid = blockIdx.x;
    int nb = bid % 3; int r = bid / 3; int e = r & 3; int tile = r >> 2;
    int n_e = counts[e];
    int t0 = tile << 7;
    if (t0 >= n_e) return;
    int eo = counts[8 + e];

    int tid = threadIdx.x, lane = tid & 63, w = tid >> 6;
    int lg = lane >> 4, l16 = lane & 15;

    int* tokp = (int*)(smem + LT);
    if (tid < 128) {
        int idx = t0 + tid; if (idx >= n_e) idx = n_e - 1;
        tokp[tid] = bucket[e * NT + idx];
    }
    __syncthreads();

    // A staging: thread -> (row=tid>>1, h=tid&1), 16 floats/step
    int arow = tid >> 1, h = tid & 1;
    const float* aptr = hidden + (size_t)tokp[arow] * HD + h * 16;
    unsigned aw0 = (unsigned)(arow * 80 + (((2 * h)     ^ (arow & 3)) << 4));
    unsigned aw1 = (unsigned)(arow * 80 + (((2 * h + 1) ^ (arow & 3)) << 4));

    // B GLL: 2 chunks/wave from step-image
    const unsigned char* gb = (const unsigned char*)b1s
        + (size_t)((e * 3 + nb) * 24) * 8192 + w * 1024 + lane * 16;

    // frag addressing
    unsigned laneoff = (unsigned)(((l16 >> 1) << 7) +
                       (((lg + ((l16 & 1) << 2)) ^ (l16 >> 1)) << 4));
    unsigned arb[2];
    #pragma unroll
    for (int mt = 0; mt < 2; ++mt)
        arb[mt] = (unsigned)((w * 32 + mt * 16 + l16) * 80 + ((lg ^ (l16 & 3)) << 4));

    f32x4 av[4];
    auto issueA = [&](int g) {
        const f32x4* p = (const f32x4*)(aptr + g * 32);
        av[0] = p[0]; av[1] = p[1]; av[2] = p[2]; av[3] = p[3];
    };
    auto writeA = [&](unsigned base) {
        u32x4 u0 = {pk2(av[0].x,av[0].y), pk2(av[0].z,av[0].w), pk2(av[1].x,av[1].y), pk2(av[1].z,av[1].w)};
        u32x4 u1 = {pk2(av[2].x,av[2].y), pk2(av[2].z,av[2].w), pk2(av[3].x,av[3].y), pk2(av[3].z,av[3].w)};
        *(u32x4*)(smem + base + aw0) = u0;
        *(u32x4*)(smem + base + aw1) = u1;
    };
    auto gllB = [&](int g, unsigned dst) {
        GLLD(gb + (size_t)g * 8192,        smem + dst + w * 1024);
        GLLD(gb + (size_t)g * 8192 + 4096, smem + dst + 4096 + w * 1024);
    };

    const f32x4 fzero = {0.f, 0.f, 0.f, 0.f};
    f32x4 acc[2][8];
    #pragma unroll
    for (int mt = 0; mt < 2; ++mt)
        #pragma unroll
        for (int nc = 0; nc < 8; ++nc) acc[mt][nc] = fzero;

    issueA(0); gllB(0, LB[0]); writeA(LA[0]);
    asm volatile("s_waitcnt vmcnt(0) lgkmcnt(0)");
    __builtin_amdgcn_s_barrier();
    __builtin_amdgcn_sched_barrier(0);

    #pragma unroll 1
    for (int g = 0; g < 24; ++g) {
        unsigned Ab = LA[g & 1], Bb = LB[g & 1];
        unsigned An = LA[(g + 1) & 1], Bn = LB[(g + 1) & 1];
        if (g < 23) { issueA(g + 1); gllB(g + 1, Bn); }

        bf16x8 Af[2];
        #pragma unroll
        for (int mt = 0; mt < 2; ++mt) Af[mt] = *(const bf16x8*)(smem + Ab + arb[mt]);
        __builtin_amdgcn_s_setprio(1);
        #pragma unroll
        for (int nc = 0; nc < 8; ++nc) {
            bf16x8 Bf = *(const bf16x8*)(smem + Bb + nc * 1024 + laneoff);
            #pragma unroll
            for (int mt = 0; mt < 2; ++mt)
                acc[mt][nc] = __builtin_amdgcn_mfma_f32_16x16x32_bf16(Af[mt], Bf, acc[mt][nc], 0, 0, 0);
        }
        __builtin_amdgcn_s_setprio(0);

        if (g < 23) {
            writeA(An);
            asm volatile("s_waitcnt vmcnt(0) lgkmcnt(0)");
            __builtin_amdgcn_s_barrier();
            __builtin_amdgcn_sched_barrier(0);
        }
    }

    // epilogue: silu(gate)*up -> act (compact index eo+t0+row, f = nb*64 + nc*16 + l16)
    #pragma unroll
    for (int mt = 0; mt < 2; ++mt)
        #pragma unroll
        for (int p = 0; p < 4; ++p) {
            int row = w * 32 + mt * 16 + 4 * lg + p;
            if (t0 + row < n_e) {
                unsigned short* arowp = act + (size_t)(eo + t0 + row) * F1 + nb * 64 + l16;
                #pragma unroll
                for (int nc = 0; nc < 4; ++nc) {
                    float g_ = acc[mt][nc][p], u_ = acc[mt][nc + 4][p];
                    float a_ = g_ / (1.f + __expf(-g_)) * u_;
                    arowp[nc * 16] = f2bf(a_);
                }
            }
        }
}

// ======= GEMM2: 256 thr, 3 blocks/CU; block = 128 tok x 128 out-cols, K=192 =======
__global__ __launch_bounds__(256, 3)
void gemm2_kernel(const int* __restrict__ counts, const int* __restrict__ bucket,
                  const unsigned short* __restrict__ dns, const unsigned short* __restrict__ act,
                  float* __restrict__ out)
{
    __shared__ __align__(16) unsigned char smem[33280];
    const unsigned LA[2] = {0u, 8192u};            // A: [ko4][row128] 16B units
    const unsigned LB[2] = {16384u, 24576u};
    const unsigned LT = 32768u;

    int bid = blockIdx.x;
    int nb = bid % 6; int r = bid / 6; int e = r & 3; int tile = r >> 2;
    int n_e = counts[e];
    int t0 = tile << 7;
    if (t0 >= n_e) return;
    int eo = counts[8 + e];

    int tid = threadIdx.x, lane = tid & 63, w = tid >> 6;
    int lg = lane >> 4, l16 = lane & 15;

    int* tokp = (int*)(smem + LT);
    if (tid < 128) {
        int idx = t0 + tid; if (idx >= n_e) idx = n_e - 1;
        tokp[tid] = bucket[e * NT + idx];
    }
    __syncthreads();

    // A GLL per-lane sources: unit u = ko*128+row ; thread covers u=tid and u=tid+256
    int row0 = tid & 127, ko0 = tid >> 7;
    int ar = t0 + row0; if (ar >= n_e) ar = n_e - 1;
    const unsigned short* as0 = act + (size_t)(eo + ar) * F1 + ko0 * 8;    // + ks*32 per step
    const unsigned short* as1 = as0 + 16;                                   // ko0+2
    // B GLL
    const unsigned char* gb = (const unsigned char*)dns
        + (size_t)((e * 6 + nb) * 6) * 8192 + w * 1024 + lane * 16;

    unsigned laneoff = (unsigned)(((l16 >> 1) << 7) +
                       (((lg + ((l16 & 1) << 2)) ^ (l16 >> 1)) << 4));
    unsigned arb[2];
    #pragma unroll
    for (int mt = 0; mt < 2; ++mt)
        arb[mt] = (unsigned)(lg * 2048 + (w * 32 + mt * 16 + l16) * 16);

    auto gllA = [&](int s, unsigned dst) {
        GLLD(as0 + s * 32, smem + dst + w * 1024);
        GLLD(as1 + s * 32, smem + dst + 4096 + w * 1024);
    };
    auto gllB = [&](int s, unsigned dst) {
        GLLD(gb + (size_t)s * 8192,        smem + dst + w * 1024);
        GLLD(gb + (size_t)s * 8192 + 4096, smem + dst + 4096 + w * 1024);
    };

    const f32x4 fzero = {0.f, 0.f, 0.f, 0.f};
    f32x4 acc[2][8];
    #pragma unroll
    for (int mt = 0; mt < 2; ++mt)
        #pragma unroll
        for (int nc = 0; nc < 8; ++nc) acc[mt][nc] = fzero;

    gllA(0, LA[0]); gllB(0, LB[0]);
    asm volatile("s_waitcnt vmcnt(0) lgkmcnt(0)");
    __builtin_amdgcn_s_barrier();
    __builtin_amdgcn_sched_barrier(0);

    #pragma unroll 1
    for (int s = 0; s < 6; ++s) {
        unsigned Ab = LA[s & 1], Bb = LB[s & 1];
        unsigned An = LA[(s + 1) & 1], Bn = LB[(s + 1) & 1];
        if (s < 5) { gllA(s + 1, An); gllB(s + 1, Bn); }

        bf16x8 Af[2];
        #pragma unroll
        for (int mt = 0; mt < 2; ++mt) Af[mt] = *(const bf16x8*)(smem + Ab + arb[mt]);
        __builtin_amdgcn_s_setprio(1);
        #pragma unroll
        for (int nc = 0; nc < 8; ++nc) {
            bf16x8 Bf = *(const bf16x8*)(smem + Bb + nc * 1024 + laneoff);
            #pragma unroll
            for (int mt = 0; mt < 2; ++mt)
                acc[mt][nc] = __builtin_amdgcn_mfma_f32_16x16x32_bf16(Af[mt], Bf, acc[mt][nc], 0, 0, 0);
        }
        __builtin_amdgcn_s_setprio(0);

        if (s < 5) {
            asm volatile("s_waitcnt vmcnt(0) lgkmcnt(0)");
            __builtin_amdgcn_s_barrier();
            __builtin_amdgcn_sched_barrier(0);
        }
    }

    #pragma unroll
    for (int mt = 0; mt < 2; ++mt)
        #pragma unroll
        for (int p = 0; p < 4; ++p) {
            int row = w * 32 + mt * 16 + 4 * lg + p;
            if (t0 + row < n_e) {
                float* orow = out + (size_t)tokp[row] * HD + nb * 128 + l16;
                #pragma unroll
                for (int nc = 0; nc < 8; ++nc)
                    orow[nc * 16] = acc[mt][nc][p];
            }
        }
}

extern "C" void kernel_launch(void* const* d_in, const int* in_sizes, int n_in,
                              void* d_out, int out_size, void* d_ws, size_t ws_size,
                              hipStream_t stream) {
    (void)in_sizes; (void)n_in; (void)out_size; (void)ws_size;
    const float* hidden = (const float*)d_in[0];
    const int*   ids    = (const int*)d_in[1];
    const float* gu     = (const float*)d_in[2];
    const float* dn     = (const float*)d_in[3];
    float* out = (float*)d_out;

    char* ws = (char*)d_ws;
    int* counts = (int*)ws;                       // [0..3] counts, [8..11] eoff
    int* cnt    = (int*)(ws + WS_CNT_OFF);
    int* bucket = (int*)(ws + WS_BUCKET_OFF);
    unsigned short* b1s = (unsigned short*)(ws + WS_B1_OFF);
    unsigned short* dns = (unsigned short*)(ws + WS_DN_OFF);
    unsigned short* actw = (unsigned short*)(ws + WS_ACT_OFF);

    route1_kernel<<<NT / 256, 256, 0, stream>>>(ids, cnt);
    route2_kernel<<<1, 512, 0, stream>>>(cnt, counts);
    route3_kernel<<<NT / 256, 256, 0, stream>>>(ids, cnt, bucket);
    b1s_kernel<<<576, 256, 0, stream>>>(gu, b1s);
    dns_kernel<<<288, 256, 0, stream>>>(dn, dns);
    gemm1_kernel<<<4 * 264 * 3, 256, 0, stream>>>(hidden, counts, bucket, b1s, actw);
    gemm2_kernel<<<4 * 264 * 6, 256, 0, stream>>>(counts, bucket, dns, actw, out);
}